// Round 8
// baseline (2269.299 us; speedup 1.0000x reference)
//
#include <hip/hip_runtime.h>
#include <hip/hip_fp16.h>

// LightGCN on MI355X — round 7: streaming gather with LDS-resident fp32 accumulators.
// Edges stay in bucket-packed csr_tmp (96-node dst windows); gather kernels stream
// the bucket's edges (any order) into an LDS z-tile via ds_add_f32, then apply the
// normalization in a coalesced epilogue. No ptr/csr_src/placement pass at all.
// y-space propagation: y_l = dinv .* x_l; z_{l+1} = unweighted in-gather of y_l;
// y_{l+1} = dinv^2 .* z; out = 0.25*(emb + sqrt(deg).*(y1+y2) + dinv.*z3).

#define N_NODES 150000
#define N_EDGES 2000000
#define DIM     64
#define BUCK_NODES 96                      // nodes per bucket
#define NBUCK   1563                       // ceil(150000/96); 1563*96 = 150048
#define CAP     1600                       // staged capacity (mean 1280, +8.9 sigma)
#define ZPAD    65                         // odd stride -> bank-conflict-free-ish
#define EPB     8192                       // edges per bin block
#define NBIN_BLOCKS ((N_EDGES + EPB - 1) / EPB)   // 245

// bcur[b*16] = b*CAP  (64B-strided cursors)
__global__ void init_bcur(int* __restrict__ bcur) {
    int b = blockIdx.x * blockDim.x + threadIdx.x;
    if (b < NBUCK) bcur[b * 16] = b * CAP;
}

// Block-local two-pass binning into fixed-capacity buckets (dst/96).
// Entry = (src<<7) | (dst%96).
__global__ __launch_bounds__(256) void bin_edges(const int* __restrict__ src,
                                                 const int* __restrict__ dst,
                                                 int* __restrict__ bcur,
                                                 unsigned int* __restrict__ csr_tmp) {
    __shared__ int hist[NBUCK];
    __shared__ int lcur[NBUCK];
    int t = threadIdx.x;
    int e0 = blockIdx.x * EPB;
    int n = N_EDGES - e0; if (n > EPB) n = EPB;
    for (int i = t; i < NBUCK; i += 256) hist[i] = 0;
    __syncthreads();
    for (int i = t; i < n; i += 256) {
        atomicAdd(&hist[(unsigned)dst[e0 + i] / BUCK_NODES], 1);
    }
    __syncthreads();
    for (int i = t; i < NBUCK; i += 256) {
        int h = hist[i];
        lcur[i] = (h > 0) ? atomicAdd(&bcur[i * 16], h) : 0;
    }
    __syncthreads();
    for (int i = t; i < n; i += 256) {
        unsigned int d = (unsigned)dst[e0 + i];
        int s = src[e0 + i];
        unsigned int b = d / BUCK_NODES;
        int pos = atomicAdd(&lcur[b], 1);
        csr_tmp[pos] = ((unsigned int)s << 7) | (d - b * BUCK_NODES);
    }
}

// Per bucket: LDS degree hist -> dinv; then y0 = dinv .* emb (fp16), coalesced.
__global__ __launch_bounds__(256) void bucket_deg_y0(const int* __restrict__ bcur,
                                                     const unsigned int* __restrict__ csr_tmp,
                                                     const float* __restrict__ emb,
                                                     float* __restrict__ dinv,
                                                     __half* __restrict__ y0) {
    __shared__ int hist[BUCK_NODES];
    __shared__ float ldinv[BUCK_NODES];
    int b = blockIdx.x;
    int t = threadIdx.x;
    int cnt  = bcur[b * 16] - b * CAP;
    int base = b * CAP;
    if (t < BUCK_NODES) hist[t] = 0;
    __syncthreads();
    for (int j = t; j < cnt; j += 256)
        atomicAdd(&hist[csr_tmp[base + j] & 127u], 1);
    __syncthreads();
    int node0 = b * BUCK_NODES;
    if (t < BUCK_NODES) {
        int c = hist[t];
        float dv = (c > 0) ? (1.0f / sqrtf((float)c)) : 0.0f;
        ldinv[t] = dv;
        int nd = node0 + t;
        if (nd < N_NODES) dinv[nd] = dv;
    }
    __syncthreads();
    for (int i = t; i < BUCK_NODES * 8; i += 256) {
        int node = i >> 3, sub = i & 7;
        int nd = node0 + node;
        if (nd >= N_NODES) continue;
        float dv = ldinv[node];
        size_t off = ((size_t)nd << 6) + (sub << 3);
        const float4 e0 = *reinterpret_cast<const float4*>(emb + off);
        const float4 e1 = *reinterpret_cast<const float4*>(emb + off + 4);
        uint4 o;
        __half2* oh = reinterpret_cast<__half2*>(&o);
        oh[0] = __float22half2_rn(make_float2(e0.x * dv, e0.y * dv));
        oh[1] = __float22half2_rn(make_float2(e0.z * dv, e0.w * dv));
        oh[2] = __float22half2_rn(make_float2(e1.x * dv, e1.y * dv));
        oh[3] = __float22half2_rn(make_float2(e1.z * dv, e1.w * dv));
        *reinterpret_cast<uint4*>(y0 + off) = o;
    }
}

// Streaming gather: one block per bucket; z[96][65] fp32 in LDS; 8 lanes/edge
// load a 16B row slice and ds_add_f32 into the dst row. Epilogue: y = dinv^2 * z.
__global__ __launch_bounds__(256) void gather_layer(const int* __restrict__ bcur,
                                                    const unsigned int* __restrict__ csr_tmp,
                                                    const float* __restrict__ dinv,
                                                    const __half* __restrict__ yin,
                                                    __half* __restrict__ yout) {
    __shared__ float z[BUCK_NODES * ZPAD];
    int b = blockIdx.x;
    int t = threadIdx.x;
    int cnt  = bcur[b * 16] - b * CAP;
    int base = b * CAP;
    for (int i = t; i < BUCK_NODES * ZPAD; i += 256) z[i] = 0.0f;
    __syncthreads();
    int g = t >> 3, sub = t & 7;      // 32 edge-groups of 8 lanes
    for (int j = g; j < cnt; j += 32) {
        unsigned int p = csr_tmp[base + j];
        int ldst = (int)(p & 127u);
        int s    = (int)(p >> 7);
        const uint4 v = *reinterpret_cast<const uint4*>(yin + ((size_t)s << 6) + (sub << 3));
        const __half2* h = reinterpret_cast<const __half2*>(&v);
        float* zr = &z[ldst * ZPAD + sub * 8];
        float2 f;
        f = __half22float2(h[0]); atomicAdd(zr + 0, f.x); atomicAdd(zr + 1, f.y);
        f = __half22float2(h[1]); atomicAdd(zr + 2, f.x); atomicAdd(zr + 3, f.y);
        f = __half22float2(h[2]); atomicAdd(zr + 4, f.x); atomicAdd(zr + 5, f.y);
        f = __half22float2(h[3]); atomicAdd(zr + 6, f.x); atomicAdd(zr + 7, f.y);
    }
    __syncthreads();
    int node0 = b * BUCK_NODES;
    for (int i = t; i < BUCK_NODES * 8; i += 256) {
        int node = i >> 3, sb = i & 7;
        int nd = node0 + node;
        if (nd >= N_NODES) continue;
        float dv = dinv[nd];
        float w = dv * dv;
        const float* zr = &z[node * ZPAD + sb * 8];
        uint4 o;
        __half2* oh = reinterpret_cast<__half2*>(&o);
        oh[0] = __float22half2_rn(make_float2(zr[0] * w, zr[1] * w));
        oh[1] = __float22half2_rn(make_float2(zr[2] * w, zr[3] * w));
        oh[2] = __float22half2_rn(make_float2(zr[4] * w, zr[5] * w));
        oh[3] = __float22half2_rn(make_float2(zr[6] * w, zr[7] * w));
        *reinterpret_cast<uint4*>(yout + ((size_t)nd << 6) + (sb << 3)) = o;
    }
}

// Final layer: z3 from y2 stream; out = 0.25*(emb + sqrt(deg)*(y1+y2) + dinv*z3), fp32.
__global__ __launch_bounds__(256) void gather_final(const int* __restrict__ bcur,
                                                    const unsigned int* __restrict__ csr_tmp,
                                                    const float* __restrict__ dinv,
                                                    const __half* __restrict__ y2,
                                                    const __half* __restrict__ y1,
                                                    const float* __restrict__ emb,
                                                    float* __restrict__ out) {
    __shared__ float z[BUCK_NODES * ZPAD];
    int b = blockIdx.x;
    int t = threadIdx.x;
    int cnt  = bcur[b * 16] - b * CAP;
    int base = b * CAP;
    for (int i = t; i < BUCK_NODES * ZPAD; i += 256) z[i] = 0.0f;
    __syncthreads();
    int g = t >> 3, sub = t & 7;
    for (int j = g; j < cnt; j += 32) {
        unsigned int p = csr_tmp[base + j];
        int ldst = (int)(p & 127u);
        int s    = (int)(p >> 7);
        const uint4 v = *reinterpret_cast<const uint4*>(y2 + ((size_t)s << 6) + (sub << 3));
        const __half2* h = reinterpret_cast<const __half2*>(&v);
        float* zr = &z[ldst * ZPAD + sub * 8];
        float2 f;
        f = __half22float2(h[0]); atomicAdd(zr + 0, f.x); atomicAdd(zr + 1, f.y);
        f = __half22float2(h[1]); atomicAdd(zr + 2, f.x); atomicAdd(zr + 3, f.y);
        f = __half22float2(h[2]); atomicAdd(zr + 4, f.x); atomicAdd(zr + 5, f.y);
        f = __half22float2(h[3]); atomicAdd(zr + 6, f.x); atomicAdd(zr + 7, f.y);
    }
    __syncthreads();
    int node0 = b * BUCK_NODES;
    for (int i = t; i < BUCK_NODES * 8; i += 256) {
        int node = i >> 3, sb = i & 7;
        int nd = node0 + node;
        if (nd >= N_NODES) continue;
        float dv = dinv[nd];
        float sq = (dv > 0.0f) ? (1.0f / dv) : 0.0f;   // sqrt(deg)
        size_t off = ((size_t)nd << 6) + (sb << 3);
        const float4 e0 = *reinterpret_cast<const float4*>(emb + off);
        const float4 e1 = *reinterpret_cast<const float4*>(emb + off + 4);
        const uint4 v1 = *reinterpret_cast<const uint4*>(y1 + off);
        const uint4 v2 = *reinterpret_cast<const uint4*>(y2 + off);
        const __half2* h1 = reinterpret_cast<const __half2*>(&v1);
        const __half2* h2 = reinterpret_cast<const __half2*>(&v2);
        const float* zr = &z[node * ZPAD + sb * 8];
        float e[8] = {e0.x, e0.y, e0.z, e0.w, e1.x, e1.y, e1.z, e1.w};
        float r[8];
#pragma unroll
        for (int k = 0; k < 4; ++k) {
            float2 f1 = __half22float2(h1[k]);
            float2 f2 = __half22float2(h2[k]);
            r[2 * k]     = 0.25f * (e[2 * k]     + sq * (f1.x + f2.x) + dv * zr[2 * k]);
            r[2 * k + 1] = 0.25f * (e[2 * k + 1] + sq * (f1.y + f2.y) + dv * zr[2 * k + 1]);
        }
        *reinterpret_cast<float4*>(out + off)     = make_float4(r[0], r[1], r[2], r[3]);
        *reinterpret_cast<float4*>(out + off + 4) = make_float4(r[4], r[5], r[6], r[7]);
    }
}

extern "C" void kernel_launch(void* const* d_in, const int* in_sizes, int n_in,
                              void* d_out, int out_size, void* d_ws, size_t ws_size,
                              hipStream_t stream) {
    const int*   edge = (const int*)d_in[0];
    const int*   src  = edge;
    const int*   dst  = edge + N_EDGES;
    const float* emb  = (const float*)d_in[1];
    float* out = (float*)d_out;

    // Workspace layout (64B-aligned). Total ~68.3 MB.
    char* ws = (char*)d_ws;
    int*          bcur    = (int*)(ws + 0);            // NBUCK*16 ints (64B-strided)
    float*        dinv    = (float*)(ws + 100032);     // N floats
    unsigned int* csr_tmp = (unsigned int*)(ws + 700032);    // NBUCK*CAP entries
    __half*       y0      = (__half*)(ws + 10703232);  // N*D halves
    __half*       y1      = (__half*)(ws + 29903232);  // N*D halves
    __half*       y2      = (__half*)(ws + 49103232);  // N*D halves

    const int B = 256;

    // --- bucket-packed edge staging (no ptr, no placement) ---
    init_bcur<<<(NBUCK + B - 1) / B, B, 0, stream>>>(bcur);
    bin_edges<<<NBIN_BLOCKS, B, 0, stream>>>(src, dst, bcur, csr_tmp);
    bucket_deg_y0<<<NBUCK, B, 0, stream>>>(bcur, csr_tmp, emb, dinv, y0);

    // --- 3 propagation layers: streaming LDS-atomic gathers ---
    gather_layer<<<NBUCK, B, 0, stream>>>(bcur, csr_tmp, dinv, y0, y1);
    gather_layer<<<NBUCK, B, 0, stream>>>(bcur, csr_tmp, dinv, y1, y2);
    gather_final<<<NBUCK, B, 0, stream>>>(bcur, csr_tmp, dinv, y2, y1, emb, out);
}

// Round 9
// 197.952 us; speedup vs baseline: 11.4639x; 11.4639x over previous
//
#include <hip/hip_runtime.h>
#include <hip/hip_fp16.h>

// LightGCN on MI355X — round 8: revert to r7 structure (register-accum gathers);
// 8-deep pipelined gather loops; init_y0 fused into bucket_place.
// y-space propagation: y_l = dinv .* x_l; z_{l+1} = unweighted in-gather of y_l;
// y_{l+1} = dinv^2 .* z; out = 0.25*(emb + sqrt(deg).*(y1+y2) + dinv.*z3).

#define N_NODES 150000
#define N_EDGES 2000000
#define DIM     64
#define BUCK_SHIFT 9
#define BUCK_NODES 512                    // nodes per bucket
#define NBUCK   293                       // ceil(150000/512)
#define CAP     8192                      // staged capacity per bucket (mean 6826, +16 sigma)
#define EPB     8192                      // edges per bin block
#define NBIN_BLOCKS ((N_EDGES + EPB - 1) / EPB)   // 245

// bcur[b*16] = b*CAP  (64B-strided cursors, no ptr dependency)
__global__ void init_bcur(int* __restrict__ bcur) {
    int b = blockIdx.x * blockDim.x + threadIdx.x;
    if (b < NBUCK) bcur[b * 16] = b * CAP;
}

// Phase 1: block-local two-pass binning (one global atomic per block,bucket).
// Entry = (src<<9) | (dst&511); every csr_tmp line written by one CU.
__global__ __launch_bounds__(256) void bin_edges3(const int* __restrict__ src,
                                                  const int* __restrict__ dst,
                                                  int* __restrict__ bcur,
                                                  unsigned int* __restrict__ csr_tmp) {
    __shared__ int hist[NBUCK];
    __shared__ int lcur[NBUCK];
    int t = threadIdx.x;
    int e0 = blockIdx.x * EPB;
    int n = N_EDGES - e0; if (n > EPB) n = EPB;
    for (int i = t; i < NBUCK; i += 256) hist[i] = 0;
    __syncthreads();
    for (int i = t; i < n; i += 256) {
        atomicAdd(&hist[dst[e0 + i] >> BUCK_SHIFT], 1);
    }
    __syncthreads();
    for (int i = t; i < NBUCK; i += 256) {
        int h = hist[i];
        lcur[i] = (h > 0) ? atomicAdd(&bcur[i * 16], h) : 0;
    }
    __syncthreads();
    for (int i = t; i < n; i += 256) {
        int d = dst[e0 + i];
        int s = src[e0 + i];
        int b = d >> BUCK_SHIFT;
        int pos = atomicAdd(&lcur[b], 1);
        csr_tmp[pos] = ((unsigned int)s << BUCK_SHIFT) | (unsigned int)(d & (BUCK_NODES - 1));
    }
}

// Tiny scan over the 293 bucket counts -> bucket bases; ptr[N] = total (= E).
__global__ __launch_bounds__(512) void bucket_scan(const int* __restrict__ bcur,
                                                   int* __restrict__ bbase,
                                                   int* __restrict__ ptrN) {
    __shared__ int s[512];
    int t = threadIdx.x;
    int c = (t < NBUCK) ? (bcur[t * 16] - t * CAP) : 0;
    s[t] = c;
    __syncthreads();
    for (int off = 1; off < 512; off <<= 1) {
        int u = (t >= off) ? s[t - off] : 0;
        __syncthreads();
        s[t] += u;
        __syncthreads();
    }
    if (t < NBUCK) bbase[t] = s[t] - c;   // exclusive
    if (t == 511) *ptrN = s[511];
}

// Phase 2: one block per bucket. LDS hist over 512 local nodes + LDS scan ->
// ptr/dinv; place edges via LDS cursors; then y0 = dinv .* emb for the bucket
// (fused — ldinv already resident in LDS).
__global__ __launch_bounds__(256) void bucket_place3(const int* __restrict__ bcur,
                                                     const int* __restrict__ bbase,
                                                     const unsigned int* __restrict__ csr_tmp,
                                                     int* __restrict__ csr_src,
                                                     int* __restrict__ ptr,
                                                     float* __restrict__ dinv,
                                                     const float* __restrict__ emb,
                                                     __half* __restrict__ y0) {
    __shared__ int hist[BUCK_NODES];
    __shared__ int scn[BUCK_NODES];
    __shared__ int lcur[BUCK_NODES];
    __shared__ float ldinv[BUCK_NODES];
    int b = blockIdx.x;
    int t = threadIdx.x;
    int cntb = bcur[b * 16] - b * CAP;
    int base = bbase[b];
    int tmp0 = b * CAP;

    hist[t] = 0; hist[t + 256] = 0;
    __syncthreads();
    for (int j = t; j < cntb; j += 256)
        atomicAdd(&hist[csr_tmp[tmp0 + j] & (BUCK_NODES - 1)], 1);
    __syncthreads();

    // inclusive scan of 512 counts: two 256-segments + carry
    int c0 = hist[t], c1 = hist[t + 256];
    scn[t] = c0; scn[t + 256] = c1;
    __syncthreads();
    for (int off = 1; off < 256; off <<= 1) {
        int u0 = (t >= off) ? scn[t - off] : 0;
        int u1 = (t >= off) ? scn[256 + t - off] : 0;
        __syncthreads();
        scn[t] += u0; scn[256 + t] += u1;
        __syncthreads();
    }
    int carry = scn[255];
    int ex0 = scn[t] - c0;
    int ex1 = carry + scn[256 + t] - c1;

    int node0 = b * BUCK_NODES;
    int nd0 = node0 + t, nd1 = node0 + 256 + t;
    float dv0 = (c0 > 0) ? (1.0f / sqrtf((float)c0)) : 0.0f;
    float dv1 = (c1 > 0) ? (1.0f / sqrtf((float)c1)) : 0.0f;
    ldinv[t] = dv0; ldinv[t + 256] = dv1;
    if (nd0 < N_NODES) { ptr[nd0] = base + ex0; dinv[nd0] = dv0; }
    if (nd1 < N_NODES) { ptr[nd1] = base + ex1; dinv[nd1] = dv1; }
    lcur[t] = base + ex0; lcur[t + 256] = base + ex1;
    __syncthreads();

    for (int j = t; j < cntb; j += 256) {
        unsigned int p = csr_tmp[tmp0 + j];
        int local = (int)(p & (BUCK_NODES - 1));
        int pos = atomicAdd(&lcur[local], 1);
        csr_src[pos] = (int)(p >> BUCK_SHIFT);
    }

    // fused y0 = dinv .* emb for this bucket's 512 nodes (coalesced)
    for (int i = t; i < BUCK_NODES * 8; i += 256) {
        int node = i >> 3, sub = i & 7;
        int nd = node0 + node;
        if (nd >= N_NODES) continue;
        float dv = ldinv[node];
        size_t off = ((size_t)nd << 6) + (sub << 3);
        const float4 e0 = *reinterpret_cast<const float4*>(emb + off);
        const float4 e1 = *reinterpret_cast<const float4*>(emb + off + 4);
        uint4 o;
        __half2* oh = reinterpret_cast<__half2*>(&o);
        oh[0] = __float22half2_rn(make_float2(e0.x * dv, e0.y * dv));
        oh[1] = __float22half2_rn(make_float2(e0.z * dv, e0.w * dv));
        oh[2] = __float22half2_rn(make_float2(e1.x * dv, e1.y * dv));
        oh[3] = __float22half2_rn(make_float2(e1.z * dv, e1.w * dv));
        *reinterpret_cast<uint4*>(y0 + off) = o;
    }
}

__device__ __forceinline__ void acc8(float* a, const uint4& v) {
    const __half2* h = reinterpret_cast<const __half2*>(&v);
    float2 f;
    f = __half22float2(h[0]); a[0] += f.x; a[1] += f.y;
    f = __half22float2(h[1]); a[2] += f.x; a[3] += f.y;
    f = __half22float2(h[2]); a[4] += f.x; a[5] += f.y;
    f = __half22float2(h[3]); a[6] += f.x; a[7] += f.y;
}

// One 8-lane group per node; lane q owns dims [8q, 8q+8). 8-deep pipelined loop.
__global__ void gather_layer_h(const int* __restrict__ ptr,
                               const int* __restrict__ csr_src,
                               const float* __restrict__ dinv,
                               const __half* __restrict__ yin,
                               __half* __restrict__ yout) {
    int tid = blockIdx.x * blockDim.x + threadIdx.x;
    int node = tid >> 3;
    int q    = tid & 7;
    if (node >= N_NODES) return;
    int beg = ptr[node], end = ptr[node + 1];
    int qo = q << 3;
    float a[8] = {0.f, 0.f, 0.f, 0.f, 0.f, 0.f, 0.f, 0.f};
    int j = beg;
    for (; j + 8 <= end; j += 8) {
        int s0 = csr_src[j];     int s1 = csr_src[j + 1];
        int s2 = csr_src[j + 2]; int s3 = csr_src[j + 3];
        int s4 = csr_src[j + 4]; int s5 = csr_src[j + 5];
        int s6 = csr_src[j + 6]; int s7 = csr_src[j + 7];
        uint4 v0 = *reinterpret_cast<const uint4*>(yin + ((size_t)s0 << 6) + qo);
        uint4 v1 = *reinterpret_cast<const uint4*>(yin + ((size_t)s1 << 6) + qo);
        uint4 v2 = *reinterpret_cast<const uint4*>(yin + ((size_t)s2 << 6) + qo);
        uint4 v3 = *reinterpret_cast<const uint4*>(yin + ((size_t)s3 << 6) + qo);
        uint4 v4 = *reinterpret_cast<const uint4*>(yin + ((size_t)s4 << 6) + qo);
        uint4 v5 = *reinterpret_cast<const uint4*>(yin + ((size_t)s5 << 6) + qo);
        uint4 v6 = *reinterpret_cast<const uint4*>(yin + ((size_t)s6 << 6) + qo);
        uint4 v7 = *reinterpret_cast<const uint4*>(yin + ((size_t)s7 << 6) + qo);
        acc8(a, v0); acc8(a, v1); acc8(a, v2); acc8(a, v3);
        acc8(a, v4); acc8(a, v5); acc8(a, v6); acc8(a, v7);
    }
    for (; j + 4 <= end; j += 4) {
        int s0 = csr_src[j];     int s1 = csr_src[j + 1];
        int s2 = csr_src[j + 2]; int s3 = csr_src[j + 3];
        uint4 v0 = *reinterpret_cast<const uint4*>(yin + ((size_t)s0 << 6) + qo);
        uint4 v1 = *reinterpret_cast<const uint4*>(yin + ((size_t)s1 << 6) + qo);
        uint4 v2 = *reinterpret_cast<const uint4*>(yin + ((size_t)s2 << 6) + qo);
        uint4 v3 = *reinterpret_cast<const uint4*>(yin + ((size_t)s3 << 6) + qo);
        acc8(a, v0); acc8(a, v1); acc8(a, v2); acc8(a, v3);
    }
    for (; j < end; ++j) {
        int sn = csr_src[j];
        uint4 v = *reinterpret_cast<const uint4*>(yin + ((size_t)sn << 6) + qo);
        acc8(a, v);
    }
    float dv = dinv[node];
    float w = dv * dv;
    uint4 o;
    __half2* oh = reinterpret_cast<__half2*>(&o);
    oh[0] = __float22half2_rn(make_float2(a[0] * w, a[1] * w));
    oh[1] = __float22half2_rn(make_float2(a[2] * w, a[3] * w));
    oh[2] = __float22half2_rn(make_float2(a[4] * w, a[5] * w));
    oh[3] = __float22half2_rn(make_float2(a[6] * w, a[7] * w));
    *reinterpret_cast<uint4*>(yout + ((size_t)node << 6) + qo) = o;
}

// Final: z3 gather from y2; out = 0.25*(emb + sq*(y1+y2) + dinv*z3), fp32.
__global__ void gather_final_h(const int* __restrict__ ptr,
                               const int* __restrict__ csr_src,
                               const float* __restrict__ dinv,
                               const __half* __restrict__ y2,
                               const __half* __restrict__ y1,
                               const float* __restrict__ emb,
                               float* __restrict__ out) {
    int tid = blockIdx.x * blockDim.x + threadIdx.x;
    int node = tid >> 3;
    int q    = tid & 7;
    if (node >= N_NODES) return;
    int beg = ptr[node], end = ptr[node + 1];
    int qo = q << 3;
    float a[8] = {0.f, 0.f, 0.f, 0.f, 0.f, 0.f, 0.f, 0.f};
    int j = beg;
    for (; j + 8 <= end; j += 8) {
        int s0 = csr_src[j];     int s1 = csr_src[j + 1];
        int s2 = csr_src[j + 2]; int s3 = csr_src[j + 3];
        int s4 = csr_src[j + 4]; int s5 = csr_src[j + 5];
        int s6 = csr_src[j + 6]; int s7 = csr_src[j + 7];
        uint4 v0 = *reinterpret_cast<const uint4*>(y2 + ((size_t)s0 << 6) + qo);
        uint4 v1 = *reinterpret_cast<const uint4*>(y2 + ((size_t)s1 << 6) + qo);
        uint4 v2 = *reinterpret_cast<const uint4*>(y2 + ((size_t)s2 << 6) + qo);
        uint4 v3 = *reinterpret_cast<const uint4*>(y2 + ((size_t)s3 << 6) + qo);
        uint4 v4 = *reinterpret_cast<const uint4*>(y2 + ((size_t)s4 << 6) + qo);
        uint4 v5 = *reinterpret_cast<const uint4*>(y2 + ((size_t)s5 << 6) + qo);
        uint4 v6 = *reinterpret_cast<const uint4*>(y2 + ((size_t)s6 << 6) + qo);
        uint4 v7 = *reinterpret_cast<const uint4*>(y2 + ((size_t)s7 << 6) + qo);
        acc8(a, v0); acc8(a, v1); acc8(a, v2); acc8(a, v3);
        acc8(a, v4); acc8(a, v5); acc8(a, v6); acc8(a, v7);
    }
    for (; j + 4 <= end; j += 4) {
        int s0 = csr_src[j];     int s1 = csr_src[j + 1];
        int s2 = csr_src[j + 2]; int s3 = csr_src[j + 3];
        uint4 v0 = *reinterpret_cast<const uint4*>(y2 + ((size_t)s0 << 6) + qo);
        uint4 v1 = *reinterpret_cast<const uint4*>(y2 + ((size_t)s1 << 6) + qo);
        uint4 v2 = *reinterpret_cast<const uint4*>(y2 + ((size_t)s2 << 6) + qo);
        uint4 v3 = *reinterpret_cast<const uint4*>(y2 + ((size_t)s3 << 6) + qo);
        acc8(a, v0); acc8(a, v1); acc8(a, v2); acc8(a, v3);
    }
    for (; j < end; ++j) {
        int sn = csr_src[j];
        uint4 v = *reinterpret_cast<const uint4*>(y2 + ((size_t)sn << 6) + qo);
        acc8(a, v);
    }
    float dv = dinv[node];
    float sq = (dv > 0.f) ? (1.0f / dv) : 0.0f;   // sqrt(deg), 0 for deg-0

    size_t off = ((size_t)node << 6) + qo;
    const float4 e0 = *reinterpret_cast<const float4*>(emb + off);
    const float4 e1 = *reinterpret_cast<const float4*>(emb + off + 4);
    const uint4 v1 = *reinterpret_cast<const uint4*>(y1 + off);
    const uint4 v2 = *reinterpret_cast<const uint4*>(y2 + off);
    const __half2* h1 = reinterpret_cast<const __half2*>(&v1);
    const __half2* h2 = reinterpret_cast<const __half2*>(&v2);

    float e[8] = {e0.x, e0.y, e0.z, e0.w, e1.x, e1.y, e1.z, e1.w};
    float r[8];
#pragma unroll
    for (int k = 0; k < 4; ++k) {
        float2 f1 = __half22float2(h1[k]);
        float2 f2 = __half22float2(h2[k]);
        r[2 * k]     = 0.25f * (e[2 * k]     + sq * (f1.x + f2.x) + dv * a[2 * k]);
        r[2 * k + 1] = 0.25f * (e[2 * k + 1] + sq * (f1.y + f2.y) + dv * a[2 * k + 1]);
    }
    *reinterpret_cast<float4*>(out + off)     = make_float4(r[0], r[1], r[2], r[3]);
    *reinterpret_cast<float4*>(out + off + 4) = make_float4(r[4], r[5], r[6], r[7]);
}

extern "C" void kernel_launch(void* const* d_in, const int* in_sizes, int n_in,
                              void* d_out, int out_size, void* d_ws, size_t ws_size,
                              hipStream_t stream) {
    const int*   edge = (const int*)d_in[0];
    const int*   src  = edge;
    const int*   dst  = edge + N_EDGES;
    const float* emb  = (const float*)d_in[1];
    float* out = (float*)d_out;

    // Workspace layout (64B-aligned). Total ~76.4 MB.
    char* ws = (char*)d_ws;
    int*          ptr     = (int*)(ws + 0);            // N+1 ints
    float*        dinv    = (float*)(ws + 600064);     // N floats
    int*          bcur    = (int*)(ws + 1200064);      // NBUCK*16 ints (64B-strided)
    int*          bbase   = (int*)(ws + 1218816);      // NBUCK ints
    int*          csr_src = (int*)(ws + 1220096);      // E ints
    unsigned int* csr_tmp = (unsigned int*)(ws + 9220096);   // NBUCK*CAP entries
    __half*       y0      = (__half*)(ws + 18821120);  // N*D halves
    __half*       y1      = (__half*)(ws + 38021120);  // N*D halves
    __half*       y2      = (__half*)(ws + 57221120);  // N*D halves

    const int B = 256;

    // --- histogram-free CSR build (+ fused y0 init) ---
    init_bcur<<<2, 256, 0, stream>>>(bcur);
    bin_edges3<<<NBIN_BLOCKS, B, 0, stream>>>(src, dst, bcur, csr_tmp);
    bucket_scan<<<1, 512, 0, stream>>>(bcur, bbase, ptr + N_NODES);
    bucket_place3<<<NBUCK, B, 0, stream>>>(bcur, bbase, csr_tmp, csr_src, ptr, dinv, emb, y0);

    // --- 3 propagation layers (8 lanes per node, 8-deep pipelined) ---
    const int nodeBlocks = (N_NODES * 8 + B - 1) / B;
    gather_layer_h<<<nodeBlocks, B, 0, stream>>>(ptr, csr_src, dinv, y0, y1);
    gather_layer_h<<<nodeBlocks, B, 0, stream>>>(ptr, csr_src, dinv, y1, y2);
    gather_final_h<<<nodeBlocks, B, 0, stream>>>(ptr, csr_src, dinv, y2, y1, emb, out);
}